// Round 11
// baseline (930.557 us; speedup 1.0000x reference)
//
#include <hip/hip_runtime.h>
#include <hip/hip_bf16.h>
#include <math.h>

#define NNODES 10000
#define NEDGES 160000
#define ETOT (NEDGES + NNODES)  // edges + self-loops
#define HEADS 7
#define CH 64
#define HC 448    // HEADS*CH
#define HCP 1024  // padded fused width: [xl 512 | xr 512], slot = half*512+c*8+h

typedef __attribute__((ext_vector_type(8))) short short8;
typedef __attribute__((ext_vector_type(4))) float floatx4;

__device__ __forceinline__ float bf_lo(unsigned u) {
  return __uint_as_float(u << 16);
}
__device__ __forceinline__ float bf_hi(unsigned u) {
  return __uint_as_float(u & 0xffff0000u);
}
__device__ __forceinline__ short f2bf(float v) {
  return __bfloat16_as_short(__float2bfloat16(v));
}

// ---------------------------------------------------------------------------
// Fused prep: x->bf16, W1/W2/W3 transpose->bf16, GAT weight pack, cnt init.
// ---------------------------------------------------------------------------
#define P0 2560000                // convert groups (4 floats each)
#define P1 (P0 + 512 * 1024)      // W1t entries
#define P2 (P1 + 256 * 512)       // W2t
#define P3 (P2 + 64 * 256)        // W3t
#define P4 (P3 + 5 * HCP * 64)    // Wgt
#define P5 (P4 + 5 * HCP)         // bg
#define P6 (P5 + NNODES)          // cnt init
#define PTOT P6

__global__ __launch_bounds__(256) void prep_kernel(
    const float* __restrict__ x, short* __restrict__ xb,
    const float* __restrict__ W1, short* __restrict__ W1t,
    const float* __restrict__ W2, short* __restrict__ W2t,
    const float* __restrict__ W3, short* __restrict__ W3t,
    const float* __restrict__ Wl, const float* __restrict__ Wr,
    const float* __restrict__ bl, short* __restrict__ Wgt,
    float* __restrict__ bg, int* __restrict__ cnt) {
  int idx = blockIdx.x * 256 + threadIdx.x;
  if (idx < P0) {
    float4 v = *(const float4*)&x[(size_t)idx * 4];
    short4 o;
    o.x = f2bf(v.x); o.y = f2bf(v.y); o.z = f2bf(v.z); o.w = f2bf(v.w);
    *(short4*)&xb[(size_t)idx * 4] = o;
  } else if (idx < P1) {
    int i = idx - P0;               // W1: K=1024, N=512
    int n = i / 1024, k = i % 1024;
    W1t[i] = f2bf(W1[(size_t)k * 512 + n]);
  } else if (idx < P2) {
    int i = idx - P1;               // W2: K=512, N=256
    int n = i / 512, k = i % 512;
    W2t[i] = f2bf(W2[(size_t)k * 256 + n]);
  } else if (idx < P3) {
    int i = idx - P2;               // W3: K=256, N=64
    int n = i / 256, k = i % 256;
    W3t[i] = f2bf(W3[(size_t)k * 64 + n]);
  } else if (idx < P4) {
    int i = idx - P3;               // Wgt[l][col'][k]
    int l = i / (HCP * 64);
    int rem = i % (HCP * 64);
    int col = rem / 64, k = rem % 64;
    int half = col >> 9;
    int within = col & 511;
    int c = within >> 3, h = within & 7;
    float v = 0.f;
    if (h < 7) {
      const float* W = half ? Wr : Wl;
      v = W[((size_t)l * 64 + k) * HC + h * 64 + c];
    }
    Wgt[i] = f2bf(v);
  } else if (idx < P5) {
    int i = idx - P4;
    int l = i >> 10, col = i & 1023;
    int half = col >> 9, within = col & 511;
    int c = within >> 3, h = within & 7;
    bg[i] = (!half && h < 7) ? bl[(size_t)l * HC + h * 64 + c] : 0.f;
  } else if (idx < P6) {
    cnt[idx - P5] = 1;  // self-loop
  }
}

// ---------------------------------------------------------------------------
// MFMA bf16 GEMM: C = act(A @ Bt^T + bias), bf16 row-major out.
// ---------------------------------------------------------------------------
template <int BM, int BN, int RELU>
__global__ __launch_bounds__(256) void mfma_gemm(
    const short* __restrict__ A, const short* __restrict__ Bt,
    const float* __restrict__ bias, short* __restrict__ C,
    int M, int K, int Nc) {
  __shared__ short As[BM * 64];
  __shared__ short Bs[BN * 64];
  constexpr int MI = BM / 32;
  constexpr int NJ = BN / 32;
  int tid = threadIdx.x;
  int lane = tid & 63, wave = tid >> 6;
  int wm = wave >> 1, wn = wave & 1;
  int row0 = blockIdx.x * BM, col0 = blockIdx.y * BN;
  floatx4 acc[MI][NJ] = {};

  for (int k0 = 0; k0 < K; k0 += 64) {
    #pragma unroll
    for (int i = 0; i < BM / 32; ++i) {
      int c = i * 4 + wave;
      int r = c * 8 + (lane >> 3);
      int k = (lane & 7) * 8;
      int grow = row0 + r;
      if (grow >= M) grow = M - 1;
      __builtin_amdgcn_global_load_lds(
          (const __attribute__((address_space(1))) void*)(A + (size_t)grow * K + k0 + k),
          (__attribute__((address_space(3))) void*)(As + c * 512), 16, 0, 0);
    }
    #pragma unroll
    for (int i = 0; i < BN / 32; ++i) {
      int c = i * 4 + wave;
      int r = c * 8 + (lane >> 3);
      int k = (lane & 7) * 8;
      int gcol = col0 + r;
      if (gcol >= Nc) gcol = Nc - 1;
      __builtin_amdgcn_global_load_lds(
          (const __attribute__((address_space(1))) void*)(Bt + (size_t)gcol * K + k0 + k),
          (__attribute__((address_space(3))) void*)(Bs + c * 512), 16, 0, 0);
    }
    __syncthreads();
    int lr = lane & 15, lq = lane >> 4;
    #pragma unroll
    for (int kk = 0; kk < 64; kk += 32) {
      short8 af[MI], bf[NJ];
      #pragma unroll
      for (int i = 0; i < MI; ++i)
        af[i] = *(const short8*)&As[(wm * (BM / 2) + i * 16 + lr) * 64 + kk + lq * 8];
      #pragma unroll
      for (int j = 0; j < NJ; ++j)
        bf[j] = *(const short8*)&Bs[(wn * (BN / 2) + j * 16 + lr) * 64 + kk + lq * 8];
      #pragma unroll
      for (int i = 0; i < MI; ++i)
        #pragma unroll
        for (int j = 0; j < NJ; ++j)
          acc[i][j] = __builtin_amdgcn_mfma_f32_16x16x32_bf16(
              af[i], bf[j], acc[i][j], 0, 0, 0);
    }
    __syncthreads();
  }

  int lr = lane & 15, lq = lane >> 4;
  #pragma unroll
  for (int j = 0; j < NJ; ++j) {
    int col = col0 + wn * (BN / 2) + j * 16 + lr;
    float bj = bias ? bias[col] : 0.f;
    #pragma unroll
    for (int i = 0; i < MI; ++i) {
      int rbase = row0 + wm * (BM / 2) + i * 16 + lq * 4;
      #pragma unroll
      for (int r = 0; r < 4; ++r) {
        int row = rbase + r;
        if (row < M) {
          float v = acc[i][j][r] + bj;
          if (RELU) v = fmaxf(v, 0.f);
          C[(size_t)row * Nc + col] = f2bf(v);
        }
      }
    }
  }
}

// ---------------------------------------------------------------------------
// CSR build (dst-grouped, self-loops included).
// ---------------------------------------------------------------------------
__global__ void hist_kernel(const int* __restrict__ ei, int* __restrict__ cnt) {
  int e = blockIdx.x * 256 + threadIdx.x;
  if (e < NEDGES) atomicAdd(&cnt[ei[NEDGES + e]], 1);
}

// single-block shuffle-based scan
__global__ __launch_bounds__(1024) void scan_kernel(
    const int* __restrict__ cnt, int* __restrict__ row_start,
    int* __restrict__ cursor) {
  __shared__ int wsum[16];
  int t = threadIdx.x;
  int lane = t & 63, w = t >> 6;
  int base = t * 10;
  int v[10], s = 0;
  #pragma unroll
  for (int i = 0; i < 10; ++i) {
    v[i] = (base + i < NNODES) ? cnt[base + i] : 0;
    s += v[i];
  }
  int incl = s;
  #pragma unroll
  for (int off = 1; off < 64; off <<= 1) {
    int o = __shfl_up(incl, off, 64);
    if (lane >= off) incl += o;
  }
  if (lane == 63) wsum[w] = incl;
  __syncthreads();
  if (w == 0) {
    int wv = (lane < 16) ? wsum[lane] : 0;
    #pragma unroll
    for (int off = 1; off < 16; off <<= 1) {
      int o = __shfl_up(wv, off, 64);
      if (lane >= off) wv += o;
    }
    if (lane < 16) wsum[lane] = wv;
  }
  __syncthreads();
  int woff = (w > 0) ? wsum[w - 1] : 0;
  int excl = woff + incl - s;
  #pragma unroll
  for (int i = 0; i < 10; ++i) {
    if (base + i < NNODES) {
      row_start[base + i] = excl;
      cursor[base + i] = excl;
    }
    excl += v[i];
  }
  if (t == 1023) row_start[NNODES] = wsum[15];
}

// merged scatter: t < NNODES -> self loop; else graph edge
__global__ void scatter_kernel(const int* __restrict__ ei,
                               int* __restrict__ cursor,
                               int* __restrict__ csr_src) {
  int t = blockIdx.x * 256 + threadIdx.x;
  if (t < NNODES) {
    int pos = atomicAdd(&cursor[t], 1);
    csr_src[pos] = t;
  } else if (t < ETOT) {
    int e = t - NNODES;
    int d = ei[NEDGES + e];
    int pos = atomicAdd(&cursor[d], 1);
    csr_src[pos] = ei[e];
  }
}

// ---------------------------------------------------------------------------
// Fused per-layer edge kernel. 2 nodes/block, 2 independent waves per node
// (contiguous edge halves) -- NO mid-loop cross-wave barriers (R9's mistake),
// NO xr register preload (R6's mistake). Per chunk of 8 edges:
//   phase A: 8-lane groups compute w=exp(logit) (max-free softmax), write to
//            a per-wave LDS strip (2-row broadcast-friendly, conflict-free;
//            same-wave DS ops are in-order -> no barrier);
//   phase B: lane=channel weighted gather of the same xl rows (L2-hot).
// End: LDS merge of the two half-waves, epilogue (FINAL=1: in-wave out-MLP).
// ---------------------------------------------------------------------------
template <int FINAL>
__global__ __launch_bounds__(256) void gat_fused2_kernel(
    const short* __restrict__ xlt, const float* __restrict__ att,
    const float* __restrict__ cbias, const int* __restrict__ row_start,
    const int* __restrict__ csr_src, short* __restrict__ hout,
    const float* __restrict__ V1, const float* __restrict__ c1,
    const float* __restrict__ V2, const float* __restrict__ c2,
    const float* __restrict__ V3, const float* __restrict__ c3,
    float* __restrict__ out) {
  __shared__ float att_s[512];       // att_t[c][h]
  __shared__ float w_s[4][64];       // per-wave weight strip
  __shared__ float part[2][14][64];  // cross-half merge
  __shared__ float hb[2][64], r1[2][32], r2[2][16], z3[2][9];

  int tid = threadIdx.x;
  int lane = tid & 63;
  int wv = tid >> 6;          // 0..3
  int nw = wv >> 1;           // node slot 0..1
  int half = wv & 1;          // edge half
  int n = blockIdx.x * 2 + nw;

  for (int i = tid; i < 512; i += 256) {
    int c = i >> 3, h = i & 7;
    att_s[i] = (h < 7) ? att[h * 64 + c] : 0.f;
  }
  __syncthreads();

  int beg = row_start[n], end = row_start[n + 1];
  int cntE = end - beg;
  int split = (cntE + 1) >> 1;
  int mybeg = beg + (half ? split : 0);
  int myend = half ? end : (beg + split);

  int eo = lane >> 3, cl = lane & 7;
  const uint4* xrp = (const uint4*)(xlt + (size_t)n * HCP + 512);

  float o0 = 0.f, o1 = 0.f, o2 = 0.f, o3 = 0.f, o4 = 0.f, o5 = 0.f, o6 = 0.f;
  float s0 = 0.f, s1 = 0.f, s2 = 0.f, s3 = 0.f, s4 = 0.f, s5 = 0.f, s6 = 0.f;

  for (int g = mybeg; g < myend; g += 8) {
    int lim = myend - g;
    if (lim > 8) lim = 8;
    int e = g + eo;
    int src = csr_src[(e < myend) ? e : (myend - 1)];

    // ---- phase A: logits -> w for up to 8 edges
    const uint4* xlp = (const uint4*)(xlt + (size_t)src * HCP);
    float a0 = 0.f, a1 = 0.f, a2 = 0.f, a3 = 0.f, a4 = 0.f, a5 = 0.f, a6 = 0.f;
    #pragma unroll
    for (int q = 0; q < 8; ++q) {
      int c = q * 8 + cl;
      uint4 a = xlp[c];
      uint4 b = xrp[c];
      float4 t0 = *(const float4*)&att_s[c * 8];
      float4 t1 = *(const float4*)&att_s[c * 8 + 4];
      float e0 = bf_lo(a.x) + bf_lo(b.x);
      float e1 = bf_hi(a.x) + bf_hi(b.x);
      float e2 = bf_lo(a.y) + bf_lo(b.y);
      float e3 = bf_hi(a.y) + bf_hi(b.y);
      float e4 = bf_lo(a.z) + bf_lo(b.z);
      float e5 = bf_hi(a.z) + bf_hi(b.z);
      float e6 = bf_lo(a.w) + bf_lo(b.w);
      e0 = fmaxf(e0, 0.2f * e0); e1 = fmaxf(e1, 0.2f * e1);
      e2 = fmaxf(e2, 0.2f * e2); e3 = fmaxf(e3, 0.2f * e3);
      e4 = fmaxf(e4, 0.2f * e4); e5 = fmaxf(e5, 0.2f * e5);
      e6 = fmaxf(e6, 0.2f * e6);
      a0 += t0.x * e0; a1 += t0.y * e1;
      a2 += t0.z * e2; a3 += t0.w * e3;
      a4 += t1.x * e4; a5 += t1.y * e5;
      a6 += t1.z * e6;
    }
    #pragma unroll
    for (int st = 1; st <= 4; st <<= 1) {
      a0 += __shfl_xor(a0, st, 64); a1 += __shfl_xor(a1, st, 64);
      a2 += __shfl_xor(a2, st, 64); a3 += __shfl_xor(a3, st, 64);
      a4 += __shfl_xor(a4, st, 64); a5 += __shfl_xor(a5, st, 64);
      a6 += __shfl_xor(a6, st, 64);
    }
    float res = 0.f;
    res = (cl == 0) ? a0 : res; res = (cl == 1) ? a1 : res;
    res = (cl == 2) ? a2 : res; res = (cl == 3) ? a3 : res;
    res = (cl == 4) ? a4 : res; res = (cl == 5) ? a5 : res;
    res = (cl == 6) ? a6 : res;
    float wgt = (cl < 7 && eo < lim) ? __expf(res) : 0.f;
    w_s[wv][eo * 8 + cl] = wgt;  // 2-way bank alias = free; same-wave in-order

    // ---- phase B: weighted gather (rows L2-hot from phase A)
    for (int t = 0; t < lim; ++t) {
      int s = __shfl(src, t * 8, 64);
      float4 wa = *(const float4*)&w_s[wv][t * 8];      // broadcast
      float4 wb = *(const float4*)&w_s[wv][t * 8 + 4];  // broadcast
      uint4 xv = *(const uint4*)(xlt + (size_t)s * HCP + (size_t)lane * 8);
      o0 += wa.x * bf_lo(xv.x);
      o1 += wa.y * bf_hi(xv.x);
      o2 += wa.z * bf_lo(xv.y);
      o3 += wa.w * bf_hi(xv.y);
      o4 += wb.x * bf_lo(xv.z);
      o5 += wb.y * bf_hi(xv.z);
      o6 += wb.z * bf_lo(xv.w);
      s0 += wa.x; s1 += wa.y; s2 += wa.z; s3 += wa.w;
      s4 += wb.x; s5 += wb.y; s6 += wb.z;
    }
  }

  // ---- merge the two half-waves per node
  if (half == 1) {
    part[nw][0][lane] = o0;  part[nw][1][lane] = o1;
    part[nw][2][lane] = o2;  part[nw][3][lane] = o3;
    part[nw][4][lane] = o4;  part[nw][5][lane] = o5;
    part[nw][6][lane] = o6;
    part[nw][7][lane] = s0;  part[nw][8][lane] = s1;
    part[nw][9][lane] = s2;  part[nw][10][lane] = s3;
    part[nw][11][lane] = s4; part[nw][12][lane] = s5;
    part[nw][13][lane] = s6;
  }
  __syncthreads();
  if (half == 0) {
    o0 += part[nw][0][lane];  o1 += part[nw][1][lane];
    o2 += part[nw][2][lane];  o3 += part[nw][3][lane];
    o4 += part[nw][4][lane];  o5 += part[nw][5][lane];
    o6 += part[nw][6][lane];
    s0 += part[nw][7][lane];  s1 += part[nw][8][lane];
    s2 += part[nw][9][lane];  s3 += part[nw][10][lane];
    s4 += part[nw][11][lane]; s5 += part[nw][12][lane];
    s6 += part[nw][13][lane];
    float accv = o0 / (s0 + 1e-16f) + o1 / (s1 + 1e-16f) + o2 / (s2 + 1e-16f) +
                 o3 / (s3 + 1e-16f) + o4 / (s4 + 1e-16f) + o5 / (s5 + 1e-16f) +
                 o6 / (s6 + 1e-16f);
    float v = fmaxf(accv * (1.0f / 7.0f) + cbias[lane], 0.f);
    if (!FINAL) {
      hout[(size_t)n * 64 + lane] = f2bf(v);
    } else {
      // ---- output MLP, all within this wave (in-order DS, no barriers) ----
      int t = lane;
      hb[nw][t] = v;
      if (t < 32) {
        float a = c1[t];
        #pragma unroll
        for (int k = 0; k < 64; ++k) a += hb[nw][k] * V1[k * 32 + t];
        r1[nw][t] = fmaxf(a, 0.f);
      }
      if (t < 16) {
        float a = c2[t];
        #pragma unroll
        for (int k = 0; k < 32; ++k) a += r1[nw][k] * V2[k * 16 + t];
        r2[nw][t] = fmaxf(a, 0.f);
      }
      if (t < 9) {
        float a = c3[t];
        #pragma unroll
        for (int k = 0; k < 16; ++k) a += r2[nw][k] * V3[k * 9 + t];
        z3[nw][t] = a;
      }
      if (t < 9) {
        float mx = z3[nw][0];
        #pragma unroll
        for (int k = 1; k < 9; ++k) mx = fmaxf(mx, z3[nw][k]);
        float s = 0.f;
        #pragma unroll
        for (int k = 0; k < 9; ++k) s += __expf(z3[nw][k] - mx);
        out[(size_t)n * 9 + t] = z3[nw][t] - mx - logf(s);
      }
    }
  }
}

// ---------------------------------------------------------------------------
extern "C" void kernel_launch(void* const* d_in, const int* in_sizes, int n_in,
                              void* d_out, int out_size, void* d_ws, size_t ws_size,
                              hipStream_t stream) {
  const float* x   = (const float*)d_in[0];
  const int*   ei  = (const int*)d_in[1];
  const float* W1  = (const float*)d_in[2];
  const float* b1  = (const float*)d_in[3];
  const float* W2  = (const float*)d_in[4];
  const float* b2  = (const float*)d_in[5];
  const float* W3  = (const float*)d_in[6];
  const float* b3  = (const float*)d_in[7];
  const float* Wl  = (const float*)d_in[8];
  const float* bl  = (const float*)d_in[9];
  const float* Wr  = (const float*)d_in[10];
  const float* att = (const float*)d_in[11];
  const float* cb  = (const float*)d_in[12];
  const float* V1  = (const float*)d_in[13];
  const float* c1  = (const float*)d_in[14];
  const float* V2  = (const float*)d_in[15];
  const float* c2  = (const float*)d_in[16];
  const float* V3  = (const float*)d_in[17];
  const float* c3  = (const float*)d_in[18];
  float* out = (float*)d_out;

  char* ws = (char*)d_ws;
  size_t off = 0;
  auto alloc = [&](size_t bytes) {
    void* p = ws + off;
    off = (off + bytes + 255) & ~(size_t)255;
    return p;
  };
  // region0 (reused): xb (20.5MB) -> h2 -> xlt [N][1024] shorts
  char* region0 = (char*)alloc((size_t)NNODES * 1024 * 2 + 1024);
  short* xb  = (short*)region0;
  short* h2  = (short*)region0;
  short* xlt = (short*)region0;
  // region1 (reused): h1 (10.2MB) -> hA/hB
  char* region1 = (char*)alloc((size_t)NNODES * 512 * 2 + 1024);
  short* h1 = (short*)region1;
  short* hA = (short*)region1;
  short* hB = hA + (size_t)NNODES * 64;
  // persistent
  short* W1t = (short*)alloc((size_t)512 * 1024 * 2);
  short* W2t = (short*)alloc((size_t)256 * 512 * 2);
  short* W3t = (short*)alloc((size_t)64 * 256 * 2);
  short* Wgt = (short*)alloc((size_t)5 * HCP * 64 * 2);
  float* bg  = (float*)alloc((size_t)5 * HCP * 4);
  int* cnt       = (int*)alloc((size_t)NNODES * 4);
  int* row_start = (int*)alloc((size_t)(NNODES + 1) * 4);
  int* cursor    = (int*)alloc((size_t)NNODES * 4);
  int* csr_src   = (int*)alloc((size_t)ETOT * 4);

  // ---- fused prep (convert + transposes + pack + cnt init)
  prep_kernel<<<(PTOT + 255) / 256, 256, 0, stream>>>(
      x, xb, W1, W1t, W2, W2t, W3, W3t, Wl, Wr, bl, Wgt, bg, cnt);

  // ---- CSR build (self-loops included)
  hist_kernel<<<(NEDGES + 255) / 256, 256, 0, stream>>>(ei, cnt);
  scan_kernel<<<1, 1024, 0, stream>>>(cnt, row_start, cursor);
  scatter_kernel<<<(ETOT + 255) / 256, 256, 0, stream>>>(ei, cursor, csr_src);

  // ---- input MLP (bf16 MFMA)
  mfma_gemm<64, 128, 1><<<dim3(157, 4), 256, 0, stream>>>(
      xb, W1t, b1, h1, NNODES, 1024, 512);
  mfma_gemm<64, 128, 1><<<dim3(157, 2), 256, 0, stream>>>(
      h1, W2t, b2, h2, NNODES, 512, 256);
  mfma_gemm<64, 64, 1><<<dim3(157, 1), 256, 0, stream>>>(
      h2, W3t, b3, hA, NNODES, 256, 64);

  // ---- 5 GATv2 layers (GEMM + fused edge kernel)
  short* hcur = hA;
  short* hnext = hB;
  for (int layer = 0; layer < 5; ++layer) {
    mfma_gemm<128, 128, 0><<<dim3(79, 8), 256, 0, stream>>>(
        hcur, Wgt + (size_t)layer * HCP * 64, bg + (size_t)layer * HCP, xlt,
        NNODES, 64, HCP);
    if (layer < 4) {
      gat_fused2_kernel<0><<<5000, 256, 0, stream>>>(
          xlt, att + (size_t)layer * HC, cb + (size_t)layer * 64,
          row_start, csr_src, hnext, V1, c1, V2, c2, V3, c3, out);
    } else {
      gat_fused2_kernel<1><<<5000, 256, 0, stream>>>(
          xlt, att + (size_t)layer * HC, cb + (size_t)layer * 64,
          row_start, csr_src, hnext, V1, c1, V2, c2, V3, c3, out);
    }
    short* tmp = hcur; hcur = hnext; hnext = tmp;
  }
}

// Round 12
// 551.075 us; speedup vs baseline: 1.6886x; 1.6886x over previous
//
#include <hip/hip_runtime.h>
#include <hip/hip_bf16.h>
#include <math.h>

#define NNODES 10000
#define NEDGES 160000
#define ETOT (NEDGES + NNODES)  // edges + self-loops
#define HEADS 7
#define CH 64
#define HC 448    // HEADS*CH
#define HCP 1024  // padded fused width: [xl 512 | xr 512], slot = half*512+c*8+h

typedef __attribute__((ext_vector_type(8))) short short8;
typedef __attribute__((ext_vector_type(4))) float floatx4;

__device__ __forceinline__ float bf_lo(unsigned u) {
  return __uint_as_float(u << 16);
}
__device__ __forceinline__ float bf_hi(unsigned u) {
  return __uint_as_float(u & 0xffff0000u);
}
__device__ __forceinline__ short f2bf(float v) {
  return __bfloat16_as_short(__float2bfloat16(v));
}

// ---------------------------------------------------------------------------
// Fused prep: x->bf16, W1/W2/W3 transpose->bf16, GAT weight pack, cnt init.
// ---------------------------------------------------------------------------
#define P0 2560000                // convert groups (4 floats each)
#define P1 (P0 + 512 * 1024)      // W1t entries
#define P2 (P1 + 256 * 512)      // W2t
#define P3 (P2 + 64 * 256)       // W3t
#define P4 (P3 + 5 * HCP * 64)    // Wgt
#define P5 (P4 + 5 * HCP)         // bg
#define P6 (P5 + NNODES)          // cnt init
#define PTOT P6

__global__ __launch_bounds__(256) void prep_kernel(
    const float* __restrict__ x, short* __restrict__ xb,
    const float* __restrict__ W1, short* __restrict__ W1t,
    const float* __restrict__ W2, short* __restrict__ W2t,
    const float* __restrict__ W3, short* __restrict__ W3t,
    const float* __restrict__ Wl, const float* __restrict__ Wr,
    const float* __restrict__ bl, short* __restrict__ Wgt,
    float* __restrict__ bg, int* __restrict__ cnt) {
  int idx = blockIdx.x * 256 + threadIdx.x;
  if (idx < P0) {
    float4 v = *(const float4*)&x[(size_t)idx * 4];
    short4 o;
    o.x = f2bf(v.x); o.y = f2bf(v.y); o.z = f2bf(v.z); o.w = f2bf(v.w);
    *(short4*)&xb[(size_t)idx * 4] = o;
  } else if (idx < P1) {
    int i = idx - P0;               // W1: K=1024, N=512
    int n = i / 1024, k = i % 1024;
    W1t[i] = f2bf(W1[(size_t)k * 512 + n]);
  } else if (idx < P2) {
    int i = idx - P1;               // W2: K=512, N=256
    int n = i / 512, k = i % 512;
    W2t[i] = f2bf(W2[(size_t)k * 256 + n]);
  } else if (idx < P3) {
    int i = idx - P2;               // W3: K=256, N=64
    int n = i / 256, k = i % 256;
    W3t[i] = f2bf(W3[(size_t)k * 64 + n]);
  } else if (idx < P4) {
    int i = idx - P3;               // Wgt[l][col'][k]
    int l = i / (HCP * 64);
    int rem = i % (HCP * 64);
    int col = rem / 64, k = rem % 64;
    int half = col >> 9;
    int within = col & 511;
    int c = within >> 3, h = within & 7;
    float v = 0.f;
    if (h < 7) {
      const float* W = half ? Wr : Wl;
      v = W[((size_t)l * 64 + k) * HC + h * 64 + c];
    }
    Wgt[i] = f2bf(v);
  } else if (idx < P5) {
    int i = idx - P4;
    int l = i >> 10, col = i & 1023;
    int half = col >> 9, within = col & 511;
    int c = within >> 3, h = within & 7;
    bg[i] = (!half && h < 7) ? bl[(size_t)l * HC + h * 64 + c] : 0.f;
  } else if (idx < P6) {
    cnt[idx - P5] = 1;  // self-loop
  }
}

// ---------------------------------------------------------------------------
// MFMA bf16 GEMM: C = act(A @ Bt^T + bias), bf16 row-major out.
// ---------------------------------------------------------------------------
template <int BM, int BN, int RELU>
__global__ __launch_bounds__(256) void mfma_gemm(
    const short* __restrict__ A, const short* __restrict__ Bt,
    const float* __restrict__ bias, short* __restrict__ C,
    int M, int K, int Nc) {
  __shared__ short As[BM * 64];
  __shared__ short Bs[BN * 64];
  constexpr int MI = BM / 32;
  constexpr int NJ = BN / 32;
  int tid = threadIdx.x;
  int lane = tid & 63, wave = tid >> 6;
  int wm = wave >> 1, wn = wave & 1;
  int row0 = blockIdx.x * BM, col0 = blockIdx.y * BN;
  floatx4 acc[MI][NJ] = {};

  for (int k0 = 0; k0 < K; k0 += 64) {
    #pragma unroll
    for (int i = 0; i < BM / 32; ++i) {
      int c = i * 4 + wave;
      int r = c * 8 + (lane >> 3);
      int k = (lane & 7) * 8;
      int grow = row0 + r;
      if (grow >= M) grow = M - 1;
      __builtin_amdgcn_global_load_lds(
          (const __attribute__((address_space(1))) void*)(A + (size_t)grow * K + k0 + k),
          (__attribute__((address_space(3))) void*)(As + c * 512), 16, 0, 0);
    }
    #pragma unroll
    for (int i = 0; i < BN / 32; ++i) {
      int c = i * 4 + wave;
      int r = c * 8 + (lane >> 3);
      int k = (lane & 7) * 8;
      int gcol = col0 + r;
      if (gcol >= Nc) gcol = Nc - 1;
      __builtin_amdgcn_global_load_lds(
          (const __attribute__((address_space(1))) void*)(Bt + (size_t)gcol * K + k0 + k),
          (__attribute__((address_space(3))) void*)(Bs + c * 512), 16, 0, 0);
    }
    __syncthreads();
    int lr = lane & 15, lq = lane >> 4;
    #pragma unroll
    for (int kk = 0; kk < 64; kk += 32) {
      short8 af[MI], bf[NJ];
      #pragma unroll
      for (int i = 0; i < MI; ++i)
        af[i] = *(const short8*)&As[(wm * (BM / 2) + i * 16 + lr) * 64 + kk + lq * 8];
      #pragma unroll
      for (int j = 0; j < NJ; ++j)
        bf[j] = *(const short8*)&Bs[(wn * (BN / 2) + j * 16 + lr) * 64 + kk + lq * 8];
      #pragma unroll
      for (int i = 0; i < MI; ++i)
        #pragma unroll
        for (int j = 0; j < NJ; ++j)
          acc[i][j] = __builtin_amdgcn_mfma_f32_16x16x32_bf16(
              af[i], bf[j], acc[i][j], 0, 0, 0);
    }
    __syncthreads();
  }

  int lr = lane & 15, lq = lane >> 4;
  #pragma unroll
  for (int j = 0; j < NJ; ++j) {
    int col = col0 + wn * (BN / 2) + j * 16 + lr;
    float bj = bias ? bias[col] : 0.f;
    #pragma unroll
    for (int i = 0; i < MI; ++i) {
      int rbase = row0 + wm * (BM / 2) + i * 16 + lq * 4;
      #pragma unroll
      for (int r = 0; r < 4; ++r) {
        int row = rbase + r;
        if (row < M) {
          float v = acc[i][j][r] + bj;
          if (RELU) v = fmaxf(v, 0.f);
          C[(size_t)row * Nc + col] = f2bf(v);
        }
      }
    }
  }
}

// ---------------------------------------------------------------------------
// CSR build (dst-grouped, self-loops included).
// ---------------------------------------------------------------------------
__global__ void hist_kernel(const int* __restrict__ ei, int* __restrict__ cnt) {
  int e = blockIdx.x * 256 + threadIdx.x;
  if (e < NEDGES) atomicAdd(&cnt[ei[NEDGES + e]], 1);
}

// single-block shuffle-based scan
__global__ __launch_bounds__(1024) void scan_kernel(
    const int* __restrict__ cnt, int* __restrict__ row_start,
    int* __restrict__ cursor) {
  __shared__ int wsum[16];
  int t = threadIdx.x;
  int lane = t & 63, w = t >> 6;
  int base = t * 10;
  int v[10], s = 0;
  #pragma unroll
  for (int i = 0; i < 10; ++i) {
    v[i] = (base + i < NNODES) ? cnt[base + i] : 0;
    s += v[i];
  }
  int incl = s;
  #pragma unroll
  for (int off = 1; off < 64; off <<= 1) {
    int o = __shfl_up(incl, off, 64);
    if (lane >= off) incl += o;
  }
  if (lane == 63) wsum[w] = incl;
  __syncthreads();
  if (w == 0) {
    int wv = (lane < 16) ? wsum[lane] : 0;
    #pragma unroll
    for (int off = 1; off < 16; off <<= 1) {
      int o = __shfl_up(wv, off, 64);
      if (lane >= off) wv += o;
    }
    if (lane < 16) wsum[lane] = wv;
  }
  __syncthreads();
  int woff = (w > 0) ? wsum[w - 1] : 0;
  int excl = woff + incl - s;
  #pragma unroll
  for (int i = 0; i < 10; ++i) {
    if (base + i < NNODES) {
      row_start[base + i] = excl;
      cursor[base + i] = excl;
    }
    excl += v[i];
  }
  if (t == 1023) row_start[NNODES] = wsum[15];
}

// merged scatter: t < NNODES -> self loop; else graph edge
__global__ void scatter_kernel(const int* __restrict__ ei,
                               int* __restrict__ cursor,
                               int* __restrict__ csr_src,
                               int* __restrict__ csr_dst) {
  int t = blockIdx.x * 256 + threadIdx.x;
  if (t < NNODES) {
    int pos = atomicAdd(&cursor[t], 1);
    csr_src[pos] = t;
    csr_dst[pos] = t;
  } else if (t < ETOT) {
    int e = t - NNODES;
    int d = ei[NEDGES + e];
    int pos = atomicAdd(&cursor[d], 1);
    csr_src[pos] = ei[e];
    csr_dst[pos] = d;
  }
}

// ---------------------------------------------------------------------------
// Pass A: edge weights w = exp(logit). 8 lanes per edge, TWO edges per group
// (16 edges/wave) for doubled memory-level parallelism. Max-free softmax.
// ---------------------------------------------------------------------------
__global__ __launch_bounds__(256) void edge_logits_kernel(
    const short* __restrict__ xlt, const float* __restrict__ att,
    const int* __restrict__ csr_src, const int* __restrict__ csr_dst,
    float* __restrict__ wbuf) {
  __shared__ float att_s[512];  // att_t[c][h]
  for (int i = threadIdx.x; i < 512; i += 256) {
    int c = i >> 3, h = i & 7;
    att_s[i] = (h < 7) ? att[h * 64 + c] : 0.f;
  }
  __syncthreads();
  int lane = threadIdx.x & 63;
  int wid = threadIdx.x >> 6;
  int eo = lane >> 3, cl = lane & 7;
  int base = (blockIdx.x * 4 + wid) * 16;
  int e0 = base + eo;
  int e1 = base + 8 + eo;
  int ec0 = (e0 < ETOT) ? e0 : (ETOT - 1);
  int ec1 = (e1 < ETOT) ? e1 : (ETOT - 1);
  int sA = csr_src[ec0], dA = csr_dst[ec0];
  int sB = csr_src[ec1], dB = csr_dst[ec1];
  const uint4* xlpA = (const uint4*)(xlt + (size_t)sA * HCP);
  const uint4* xrpA = (const uint4*)(xlt + (size_t)dA * HCP + 512);
  const uint4* xlpB = (const uint4*)(xlt + (size_t)sB * HCP);
  const uint4* xrpB = (const uint4*)(xlt + (size_t)dB * HCP + 512);
  float accA[7], accB[7];
  #pragma unroll
  for (int h = 0; h < 7; ++h) { accA[h] = 0.f; accB[h] = 0.f; }
  #pragma unroll
  for (int q = 0; q < 8; ++q) {
    int c = q * 8 + cl;
    uint4 aA = xlpA[c];
    uint4 bA = xrpA[c];
    uint4 aB = xlpB[c];
    uint4 bB = xrpB[c];
    float4 t0 = *(const float4*)&att_s[c * 8];
    float4 t1 = *(const float4*)&att_s[c * 8 + 4];
    // edge A
    {
      float e0v = bf_lo(aA.x) + bf_lo(bA.x);
      float e1v = bf_hi(aA.x) + bf_hi(bA.x);
      float e2v = bf_lo(aA.y) + bf_lo(bA.y);
      float e3v = bf_hi(aA.y) + bf_hi(bA.y);
      float e4v = bf_lo(aA.z) + bf_lo(bA.z);
      float e5v = bf_hi(aA.z) + bf_hi(bA.z);
      float e6v = bf_lo(aA.w) + bf_lo(bA.w);
      e0v = fmaxf(e0v, 0.2f * e0v); e1v = fmaxf(e1v, 0.2f * e1v);
      e2v = fmaxf(e2v, 0.2f * e2v); e3v = fmaxf(e3v, 0.2f * e3v);
      e4v = fmaxf(e4v, 0.2f * e4v); e5v = fmaxf(e5v, 0.2f * e5v);
      e6v = fmaxf(e6v, 0.2f * e6v);
      accA[0] += t0.x * e0v; accA[1] += t0.y * e1v;
      accA[2] += t0.z * e2v; accA[3] += t0.w * e3v;
      accA[4] += t1.x * e4v; accA[5] += t1.y * e5v;
      accA[6] += t1.z * e6v;
    }
    // edge B
    {
      float e0v = bf_lo(aB.x) + bf_lo(bB.x);
      float e1v = bf_hi(aB.x) + bf_hi(bB.x);
      float e2v = bf_lo(aB.y) + bf_lo(bB.y);
      float e3v = bf_hi(aB.y) + bf_hi(bB.y);
      float e4v = bf_lo(aB.z) + bf_lo(bB.z);
      float e5v = bf_hi(aB.z) + bf_hi(bB.z);
      float e6v = bf_lo(aB.w) + bf_lo(bB.w);
      e0v = fmaxf(e0v, 0.2f * e0v); e1v = fmaxf(e1v, 0.2f * e1v);
      e2v = fmaxf(e2v, 0.2f * e2v); e3v = fmaxf(e3v, 0.2f * e3v);
      e4v = fmaxf(e4v, 0.2f * e4v); e5v = fmaxf(e5v, 0.2f * e5v);
      e6v = fmaxf(e6v, 0.2f * e6v);
      accB[0] += t0.x * e0v; accB[1] += t0.y * e1v;
      accB[2] += t0.z * e2v; accB[3] += t0.w * e3v;
      accB[4] += t1.x * e4v; accB[5] += t1.y * e5v;
      accB[6] += t1.z * e6v;
    }
  }
  #pragma unroll
  for (int h = 0; h < 7; ++h) {
    accA[h] += __shfl_xor(accA[h], 1, 64);
    accA[h] += __shfl_xor(accA[h], 2, 64);
    accA[h] += __shfl_xor(accA[h], 4, 64);
    accB[h] += __shfl_xor(accB[h], 1, 64);
    accB[h] += __shfl_xor(accB[h], 2, 64);
    accB[h] += __shfl_xor(accB[h], 4, 64);
  }
  float resA = 0.f, resB = 0.f;
  #pragma unroll
  for (int h = 0; h < 7; ++h) {
    resA = (cl == h) ? accA[h] : resA;
    resB = (cl == h) ? accB[h] : resB;
  }
  float wA = (cl < 7) ? __expf(resA) : 0.f;
  float wB = (cl < 7) ? __expf(resB) : 0.f;
  if (e0 < ETOT) wbuf[(size_t)e0 * 8 + cl] = wA;  // 256B coalesced per wave
  if (e1 < ETOT) wbuf[(size_t)e1 * 8 + cl] = wB;
}

// ---------------------------------------------------------------------------
// Pass B: single-pass aggregation, TWO waves per node (stride-2 edge split),
// LDS merge. lane = channel. FINAL=1 additionally runs the output MLP
// 64->32->16->9 + log_softmax in-wave (no hout store).
// Grid: 5000 blocks x 256 thr = 2 nodes/block x 2 waves/node.
// ---------------------------------------------------------------------------
template <int FINAL>
__global__ __launch_bounds__(256) void gat_agg2_kernel(
    const short* __restrict__ xlt, const float* __restrict__ wbuf,
    const float* __restrict__ cbias, const int* __restrict__ row_start,
    const int* __restrict__ csr_src, short* __restrict__ hout,
    const float* __restrict__ V1, const float* __restrict__ c1,
    const float* __restrict__ V2, const float* __restrict__ c2,
    const float* __restrict__ V3, const float* __restrict__ c3,
    float* __restrict__ out) {
  __shared__ float part[2][14][64];  // odd-wave partials per node slot
  __shared__ float hb[2][64], r1[2][32], r2[2][16], z3[2][9];
  int lane = threadIdx.x & 63;
  int wv = threadIdx.x >> 6;  // 0..3
  int nw = wv >> 1;           // node slot 0..1
  int half = wv & 1;          // which edge half
  int n = blockIdx.x * 2 + nw;
  int beg = row_start[n], end = row_start[n + 1];

  float o0 = 0.f, o1 = 0.f, o2 = 0.f, o3 = 0.f, o4 = 0.f, o5 = 0.f, o6 = 0.f;
  float s0 = 0.f, s1 = 0.f, s2 = 0.f, s3 = 0.f, s4 = 0.f, s5 = 0.f, s6 = 0.f;
  #pragma unroll 4
  for (int e = beg + half; e < end; e += 2) {
    int src = csr_src[e];
    float4 wa = *(const float4*)&wbuf[(size_t)e * 8];      // uniform
    float4 wb = *(const float4*)&wbuf[(size_t)e * 8 + 4];  // uniform
    uint4 xv = *(const uint4*)(xlt + (size_t)src * HCP + (size_t)lane * 8);
    o0 += wa.x * bf_lo(xv.x);
    o1 += wa.y * bf_hi(xv.x);
    o2 += wa.z * bf_lo(xv.y);
    o3 += wa.w * bf_hi(xv.y);
    o4 += wb.x * bf_lo(xv.z);
    o5 += wb.y * bf_hi(xv.z);
    o6 += wb.z * bf_lo(xv.w);
    s0 += wa.x; s1 += wa.y; s2 += wa.z; s3 += wa.w;
    s4 += wb.x; s5 += wb.y; s6 += wb.z;
  }

  if (half == 1) {
    part[nw][0][lane] = o0;  part[nw][1][lane] = o1;
    part[nw][2][lane] = o2;  part[nw][3][lane] = o3;
    part[nw][4][lane] = o4;  part[nw][5][lane] = o5;
    part[nw][6][lane] = o6;
    part[nw][7][lane] = s0;  part[nw][8][lane] = s1;
    part[nw][9][lane] = s2;  part[nw][10][lane] = s3;
    part[nw][11][lane] = s4; part[nw][12][lane] = s5;
    part[nw][13][lane] = s6;
  }
  __syncthreads();
  if (half == 0) {
    o0 += part[nw][0][lane];  o1 += part[nw][1][lane];
    o2 += part[nw][2][lane];  o3 += part[nw][3][lane];
    o4 += part[nw][4][lane];  o5 += part[nw][5][lane];
    o6 += part[nw][6][lane];
    s0 += part[nw][7][lane];  s1 += part[nw][8][lane];
    s2 += part[nw][9][lane];  s3 += part[nw][10][lane];
    s4 += part[nw][11][lane]; s5 += part[nw][12][lane];
    s6 += part[nw][13][lane];
    float accv = o0 / (s0 + 1e-16f) + o1 / (s1 + 1e-16f) + o2 / (s2 + 1e-16f) +
                 o3 / (s3 + 1e-16f) + o4 / (s4 + 1e-16f) + o5 / (s5 + 1e-16f) +
                 o6 / (s6 + 1e-16f);
    float v = fmaxf(accv * (1.0f / 7.0f) + cbias[lane], 0.f);
    if (!FINAL) {
      hout[(size_t)n * 64 + lane] = f2bf(v);
    } else {
      // ---- output MLP, all within this wave (in-order DS, no barriers) ----
      int t = lane;
      hb[nw][t] = v;
      if (t < 32) {
        float a = c1[t];
        #pragma unroll
        for (int k = 0; k < 64; ++k) a += hb[nw][k] * V1[k * 32 + t];
        r1[nw][t] = fmaxf(a, 0.f);
      }
      if (t < 16) {
        float a = c2[t];
        #pragma unroll
        for (int k = 0; k < 32; ++k) a += r1[nw][k] * V2[k * 16 + t];
        r2[nw][t] = fmaxf(a, 0.f);
      }
      if (t < 9) {
        float a = c3[t];
        #pragma unroll
        for (int k = 0; k < 16; ++k) a += r2[nw][k] * V3[k * 9 + t];
        z3[nw][t] = a;
      }
      if (t < 9) {
        float mx = z3[nw][0];
        #pragma unroll
        for (int k = 1; k < 9; ++k) mx = fmaxf(mx, z3[nw][k]);
        float s = 0.f;
        #pragma unroll
        for (int k = 0; k < 9; ++k) s += __expf(z3[nw][k] - mx);
        out[(size_t)n * 9 + t] = z3[nw][t] - mx - logf(s);
      }
    }
  }
}

// ---------------------------------------------------------------------------
extern "C" void kernel_launch(void* const* d_in, const int* in_sizes, int n_in,
                              void* d_out, int out_size, void* d_ws, size_t ws_size,
                              hipStream_t stream) {
  const float* x   = (const float*)d_in[0];
  const int*   ei  = (const int*)d_in[1];
  const float* W1  = (const float*)d_in[2];
  const float* b1  = (const float*)d_in[3];
  const float* W2  = (const float*)d_in[4];
  const float* b2  = (const float*)d_in[5];
  const float* W3  = (const float*)d_in[6];
  const float* b3  = (const float*)d_in[7];
  const float* Wl  = (const float*)d_in[8];
  const float* bl  = (const float*)d_in[9];
  const float* Wr  = (const float*)d_in[10];
  const float* att = (const float*)d_in[11];
  const float* cb  = (const float*)d_in[12];
  const float* V1  = (const float*)d_in[13];
  const float* c1  = (const float*)d_in[14];
  const float* V2  = (const float*)d_in[15];
  const float* c2  = (const float*)d_in[16];
  const float* V3  = (const float*)d_in[17];
  const float* c3  = (const float*)d_in[18];
  float* out = (float*)d_out;

  char* ws = (char*)d_ws;
  size_t off = 0;
  auto alloc = [&](size_t bytes) {
    void* p = ws + off;
    off = (off + bytes + 255) & ~(size_t)255;
    return p;
  };
  // region0 (reused): xb (20.5MB) -> h2 -> xlt [N][1024] shorts
  char* region0 = (char*)alloc((size_t)NNODES * 1024 * 2 + 1024);
  short* xb  = (short*)region0;
  short* h2  = (short*)region0;
  short* xlt = (short*)region0;
  // region1 (reused): h1 (10.2MB) -> hA/hB
  char* region1 = (char*)alloc((size_t)NNODES * 512 * 2 + 1024);
  short* h1 = (short*)region1;
  short* hA = (short*)region1;
  short* hB = hA + (size_t)NNODES * 64;
  // persistent
  short* W1t = (short*)alloc((size_t)512 * 1024 * 2);
  short* W2t = (short*)alloc((size_t)256 * 512 * 2);
  short* W3t = (short*)alloc((size_t)64 * 256 * 2);
  short* Wgt = (short*)alloc((size_t)5 * HCP * 64 * 2);
  float* bg  = (float*)alloc((size_t)5 * HCP * 4);
  int* cnt       = (int*)alloc((size_t)NNODES * 4);
  int* row_start = (int*)alloc((size_t)(NNODES + 1) * 4);
  int* cursor    = (int*)alloc((size_t)NNODES * 4);
  int* csr_src   = (int*)alloc((size_t)ETOT * 4);
  int* csr_dst   = (int*)alloc((size_t)ETOT * 4);
  float* wbuf    = (float*)alloc((size_t)ETOT * 8 * 4);

  // ---- fused prep (convert + transposes + pack + cnt init)
  prep_kernel<<<(PTOT + 255) / 256, 256, 0, stream>>>(
      x, xb, W1, W1t, W2, W2t, W3, W3t, Wl, Wr, bl, Wgt, bg, cnt);

  // ---- CSR build (self-loops included)
  hist_kernel<<<(NEDGES + 255) / 256, 256, 0, stream>>>(ei, cnt);
  scan_kernel<<<1, 1024, 0, stream>>>(cnt, row_start, cursor);
  scatter_kernel<<<(ETOT + 255) / 256, 256, 0, stream>>>(ei, cursor, csr_src, csr_dst);

  // ---- input MLP (bf16 MFMA)
  mfma_gemm<64, 128, 1><<<dim3(157, 4), 256, 0, stream>>>(
      xb, W1t, b1, h1, NNODES, 1024, 512);
  mfma_gemm<64, 128, 1><<<dim3(157, 2), 256, 0, stream>>>(
      h1, W2t, b2, h2, NNODES, 512, 256);
  mfma_gemm<64, 64, 1><<<dim3(157, 1), 256, 0, stream>>>(
      h2, W3t, b3, hA, NNODES, 256, 64);

  // ---- 5 GATv2 layers
  short* hcur = hA;
  short* hnext = hB;
  for (int layer = 0; layer < 5; ++layer) {
    mfma_gemm<128, 128, 0><<<dim3(79, 8), 256, 0, stream>>>(
        hcur, Wgt + (size_t)layer * HCP * 64, bg + (size_t)layer * HCP, xlt,
        NNODES, 64, HCP);
    edge_logits_kernel<<<(ETOT + 63) / 64, 256, 0, stream>>>(
        xlt, att + (size_t)layer * HC, csr_src, csr_dst, wbuf);
    if (layer < 4) {
      gat_agg2_kernel<0><<<5000, 256, 0, stream>>>(
          xlt, wbuf, cb + (size_t)layer * 64, row_start, csr_src, hnext,
          V1, c1, V2, c2, V3, c3, out);
    } else {
      gat_agg2_kernel<1><<<5000, 256, 0, stream>>>(
          xlt, wbuf, cb + (size_t)layer * 64, row_start, csr_src, hnext,
          V1, c1, V2, c2, V3, c3, out);
    }
    short* tmp = hcur; hcur = hnext; hnext = tmp;
  }
}